// Round 3
// 580.800 us; speedup vs baseline: 1.2144x; 1.2144x over previous
//
#include <hip/hip_runtime.h>
#include <math.h>

#define H 128
#define ROWS 32          // rows per node_update block (32 consecutive n, one b)
#define ASTRIDE 264      // bf16 elems per row in Abuf (256 + 8 pad)
#define XSTRIDE 132      // fp32 elems per row in aliased XN view (264*2B == 132*4B)
#define IDXCAP 512       // LDS-staged CSR srcs per block (avg 128/256; global fallback past cap)

typedef __attribute__((ext_vector_type(8))) short short8;
typedef __attribute__((ext_vector_type(4))) float floatx4;
typedef __attribute__((ext_vector_type(4))) unsigned short ushortx4;

__device__ __forceinline__ unsigned short f2bf(float f) {
    unsigned int u = __float_as_uint(f);
    u += 0x7FFFu + ((u >> 16) & 1u);       // round-to-nearest-even
    return (unsigned short)(u >> 16);
}

// ---------------- prep: sigmoid(ew), zero counters ----------------
__global__ void prep_kernel(const float* __restrict__ ew, float* __restrict__ sigw,
                            int* __restrict__ cnt1, int* __restrict__ cnt2,
                            int N_e, int N_d) {
    int i = blockIdx.x * blockDim.x + threadIdx.x;
    if (i < N_e) { sigw[i] = 1.0f / (1.0f + expf(-ew[i])); cnt1[i] = 0; }
    if (i < N_d) cnt2[i] = 0;
}

// ---------------- prep: bf16 B-operand fragments for MFMA ----------------
// Bfrag[t][kk][lane][j] = Wcat[k = kk*32 + (lane>>4)*8 + j][n = t*16 + (lane&15)]
// where Wcat[k][n] = (k<128 ? Wself[n][k] : Wmsg[n][k-128])   (y = x @ W.T)
__global__ void wfrag_kernel(const float* __restrict__ Wself,
                             const float* __restrict__ Wmsg,
                             unsigned short* __restrict__ Bfrag) {
    int idx = blockIdx.x * blockDim.x + threadIdx.x;   // 0..32767
    int j    = idx & 7;
    int lane = (idx >> 3) & 63;
    int kk   = (idx >> 9) & 7;
    int t    = idx >> 12;
    int k = kk * 32 + ((lane >> 4) << 3) + j;
    int n = (t << 4) + (lane & 15);
    float w = (k < H) ? Wself[n * H + k] : Wmsg[n * H + (k - H)];
    Bfrag[idx] = f2bf(w);
}

// ---------------- CSR build ----------------
__global__ void hist_kernel(const int* __restrict__ e_d2e, const int* __restrict__ e_e2d,
                            int* __restrict__ cnt1, int* __restrict__ cnt2, int E) {
    int e = blockIdx.x * blockDim.x + threadIdx.x;
    if (e < E) {
        atomicAdd(&cnt1[e_d2e[E + e]], 1);
        atomicAdd(&cnt2[e_e2d[E + e]], 1);
    }
}

__global__ void scan_kernel(const int* __restrict__ cnt1, int* __restrict__ off1,
                            int* __restrict__ cur1, int N1,
                            const int* __restrict__ cnt2, int* __restrict__ off2,
                            int* __restrict__ cur2, int N2) {
    const int* cnt = blockIdx.x ? cnt2 : cnt1;
    int* off = blockIdx.x ? off2 : off1;
    int* cur = blockIdx.x ? cur2 : cur1;
    int N    = blockIdx.x ? N2 : N1;
    __shared__ int part[257];
    int tid = threadIdx.x;
    int chunk = (N + 255) / 256;
    int lo = tid * chunk, hi = min(lo + chunk, N);
    int s = 0;
    for (int i = lo; i < hi; ++i) s += cnt[i];
    part[tid] = s;
    __syncthreads();
    if (tid == 0) {
        int run = 0;
        for (int i = 0; i < 256; ++i) { int t = part[i]; part[i] = run; run += t; }
        part[256] = run;
    }
    __syncthreads();
    int run = part[tid];
    for (int i = lo; i < hi; ++i) { off[i] = run; cur[i] = run; run += cnt[i]; }
    if (tid == 0) off[N] = part[256];
}

__global__ void fill_kernel(const int* __restrict__ e_d2e, const int* __restrict__ e_e2d,
                            int* __restrict__ cur1, int* __restrict__ srcs1,
                            int* __restrict__ cur2, int* __restrict__ srcs2, int E) {
    int e = blockIdx.x * blockDim.x + threadIdx.x;
    if (e < E) {
        int p1 = atomicAdd(&cur1[e_d2e[E + e]], 1); srcs1[p1] = e_d2e[e];
        int p2 = atomicAdd(&cur2[e_e2d[E + e]], 1); srcs2[p2] = e_e2d[e];
    }
}

// ---------------- fused node update (MFMA + LDS-staged CSR) ----------------
// Block: 32 rows x 128 outputs. GEMM [32 x 256(K)] @ [256 x 128],
// A = [x_bf16 | S_bf16], B = [Wself^T; Wmsg^T] pre-fragmentized.
// Wave w owns n-tiles {2w, 2w+1}; m-tiles 0..1.
// Stage is fully float4-vectorized: a row (512B) is gathered by 32 lanes at
// 16B/lane; per-thread dependent chain = 4 passes instead of 16 row-iters.
__global__ __launch_bounds__(256, 7)
void node_update_kernel(const float* __restrict__ x,
                        const float* __restrict__ gsrc,
                        const int* __restrict__ off,
                        const int* __restrict__ srcs,
                        const float* __restrict__ sigw,     // null for phase D
                        const unsigned short* __restrict__ Bfrag,
                        const float* __restrict__ bias,
                        const float* __restrict__ gamma,
                        const float* __restrict__ beta,
                        float* __restrict__ out,
                        int nShift, int nMask, long gStride, int nrows) {
    __shared__ __align__(16) unsigned short Abuf[ROWS * ASTRIDE];
    __shared__ int idxbuf[IDXCAP];
    __shared__ int offs[ROWS + 1];
    float* XN = reinterpret_cast<float*>(Abuf);   // aliased: reused after MFMA

    const int tid  = threadIdx.x;
    const int row0 = blockIdx.x * ROWS;
    const int n0   = row0 & nMask;     // rows are 32 consecutive n of one b (N % 32 == 0)

    // ---- stage CSR offsets + source indices into LDS ----
    if (tid <= ROWS) offs[tid] = off[n0 + tid];
    __syncthreads();
    const int jbase = offs[0];
    const int jtot  = offs[ROWS] - jbase;
    const int jlds  = min(jtot, IDXCAP);
    for (int j = tid; j < jlds; j += 256) idxbuf[j] = srcs[jbase + j];
    __syncthreads();

    // ---- stage: x -> bf16, scaled gather-sum -> bf16 (float4 per lane) ----
    {
        const int l32 = tid & 31;          // 32 lanes cover a 128-col row, 4 cols each
        const int sub = tid >> 5;          // 0..7: row within pass
        const int c0  = l32 * 4;
        const float* gb = gsrc + (size_t)(row0 >> nShift) * gStride;
        const bool allLds = (jtot <= IDXCAP);
#pragma unroll
        for (int pass = 0; pass < 4; ++pass) {
            const int r  = pass * 8 + sub;
            const int rg = row0 + r;
            floatx4 xv = {0.f, 0.f, 0.f, 0.f};
            floatx4 sv = {0.f, 0.f, 0.f, 0.f};
            if (rg < nrows) {
                xv = *reinterpret_cast<const floatx4*>(&x[(size_t)rg * H + c0]);
                const int beg = offs[r] - jbase, end = offs[r + 1] - jbase;
                int j = beg;
                if (allLds) {
                    for (; j + 4 <= end; j += 4) {
                        int s0 = idxbuf[j + 0];
                        int s1 = idxbuf[j + 1];
                        int s2 = idxbuf[j + 2];
                        int s3 = idxbuf[j + 3];
                        floatx4 v0 = *reinterpret_cast<const floatx4*>(&gb[(size_t)s0 * H + c0]);
                        floatx4 v1 = *reinterpret_cast<const floatx4*>(&gb[(size_t)s1 * H + c0]);
                        floatx4 v2 = *reinterpret_cast<const floatx4*>(&gb[(size_t)s2 * H + c0]);
                        floatx4 v3 = *reinterpret_cast<const floatx4*>(&gb[(size_t)s3 * H + c0]);
                        sv += (v0 + v1) + (v2 + v3);
                    }
                    for (; j < end; ++j) {
                        int s = idxbuf[j];
                        sv += *reinterpret_cast<const floatx4*>(&gb[(size_t)s * H + c0]);
                    }
                } else {
                    for (; j < end; ++j) {   // rare: block with >IDXCAP edges
                        int s = (j < IDXCAP) ? idxbuf[j] : srcs[jbase + j];
                        sv += *reinterpret_cast<const floatx4*>(&gb[(size_t)s * H + c0]);
                    }
                }
                float scale = (sigw ? sigw[n0 + r] : 1.0f) / fmaxf((float)(end - beg), 1.0f);
                sv *= scale;
            }
            ushortx4 xb, sb;
#pragma unroll
            for (int q = 0; q < 4; ++q) { xb[q] = f2bf(xv[q]); sb[q] = f2bf(sv[q]); }
            *reinterpret_cast<ushortx4*>(&Abuf[r * ASTRIDE + c0])     = xb;
            *reinterpret_cast<ushortx4*>(&Abuf[r * ASTRIDE + H + c0]) = sb;
        }
    }
    __syncthreads();

    const int wave = tid >> 6, lane = tid & 63;
    const int quad = lane >> 4, l16 = lane & 15;

    floatx4 acc[2][2];
#pragma unroll
    for (int mt = 0; mt < 2; ++mt)
#pragma unroll
        for (int t = 0; t < 2; ++t)
            acc[mt][t] = (floatx4){0.f, 0.f, 0.f, 0.f};

    // ---- MFMA main loop: K = 256 in 8 chunks of 32 ----
    const unsigned short* bf_base = Bfrag + (size_t)(2 * wave) * 4096;  // t stride = 8*64*8
    for (int kk = 0; kk < 8; ++kk) {
        const short8 b0 = *reinterpret_cast<const short8*>(bf_base + (kk * 64 + lane) * 8);
        const short8 b1 = *reinterpret_cast<const short8*>(bf_base + 4096 + (kk * 64 + lane) * 8);
#pragma unroll
        for (int mt = 0; mt < 2; ++mt) {
            const short8 a = *reinterpret_cast<const short8*>(
                &Abuf[(16 * mt + l16) * ASTRIDE + kk * 32 + quad * 8]);
            acc[mt][0] = __builtin_amdgcn_mfma_f32_16x16x32_bf16(a, b0, acc[mt][0], 0, 0, 0);
            acc[mt][1] = __builtin_amdgcn_mfma_f32_16x16x32_bf16(a, b1, acc[mt][1], 0, 0, 0);
        }
    }
    __syncthreads();   // all Abuf reads complete before XN overwrite

    // ---- epilogue 1: bias + ReLU + fp32 residual (re-read x, L2-hot) -> XN ----
#pragma unroll
    for (int t = 0; t < 2; ++t) {
        int col = 32 * wave + 16 * t + l16;
        float bb = bias[col];
#pragma unroll
        for (int mt = 0; mt < 2; ++mt) {
#pragma unroll
            for (int reg = 0; reg < 4; ++reg) {
                int r  = 16 * mt + quad * 4 + reg;   // C/D: row = quad*4+reg, col = lane&15
                int rg = row0 + r;
                float pre = fmaxf(acc[mt][t][reg] + bb, 0.f);
                float xn  = (rg < nrows ? x[(size_t)rg * H + col] : 0.f) + pre;
                XN[r * XSTRIDE + col] = xn;
            }
        }
    }
    __syncthreads();

    // ---- epilogue 2: LayerNorm (wave handles 8 rows; lane -> cols {lane, lane+64}) ----
    {
        const int o0 = lane, o1 = lane + 64;
        const float g0 = gamma[o0], g1 = gamma[o1];
        const float be0 = beta[o0], be1 = beta[o1];
        for (int rr = 0; rr < 8; ++rr) {
            int r  = 8 * wave + rr;
            int rg = row0 + r;
            if (rg >= nrows) break;
            float xn0 = XN[r * XSTRIDE + o0];
            float xn1 = XN[r * XSTRIDE + o1];
            float s  = xn0 + xn1;
            float s2 = xn0 * xn0 + xn1 * xn1;
#pragma unroll
            for (int m = 32; m >= 1; m >>= 1) {
                s  += __shfl_xor(s, m, 64);
                s2 += __shfl_xor(s2, m, 64);
            }
            float mean = s * (1.0f / H);
            float var  = s2 * (1.0f / H) - mean * mean;
            float rstd = rsqrtf(var + 1e-5f);
            out[(size_t)rg * H + o0] = (xn0 - mean) * rstd * g0 + be0;
            out[(size_t)rg * H + o1] = (xn1 - mean) * rstd * g1 + be1;
        }
    }
}

extern "C" void kernel_launch(void* const* d_in, const int* in_sizes, int n_in,
                              void* d_out, int out_size, void* d_ws, size_t ws_size,
                              hipStream_t stream) {
    const float* hD       = (const float*)d_in[0];
    const float* hE       = (const float*)d_in[1];
    const int*   e_d2e    = (const int*)d_in[2];
    const int*   e_e2d    = (const int*)d_in[3];
    const float* ew       = (const float*)d_in[4];
    const float* W_d2e    = (const float*)d_in[5];
    const float* W_e_self = (const float*)d_in[6];
    const float* b_e      = (const float*)d_in[7];
    const float* g_e      = (const float*)d_in[8];
    const float* beta_e   = (const float*)d_in[9];
    const float* W_e2d    = (const float*)d_in[10];
    const float* W_d_self = (const float*)d_in[11];
    const float* b_d      = (const float*)d_in[12];
    const float* g_d      = (const float*)d_in[13];
    const float* beta_d   = (const float*)d_in[14];

    const int E   = in_sizes[2] / 2;
    const int N_e = in_sizes[4];
    const int Bsz = in_sizes[1] / (N_e * H);
    const int N_d = in_sizes[0] / (Bsz * H);

    float* outD = (float*)d_out;
    float* outE = (float*)d_out + (size_t)Bsz * N_d * H;

    char* p = (char*)d_ws;
    auto alloc = [&](size_t bytes) { char* r = p; p += (bytes + 255) & ~(size_t)255; return r; };
    int*   cnt1   = (int*)alloc((size_t)N_e * 4);
    int*   off1   = (int*)alloc((size_t)(N_e + 1) * 4);
    int*   cur1   = (int*)alloc((size_t)N_e * 4);
    int*   srcs1  = (int*)alloc((size_t)E * 4);
    int*   cnt2   = (int*)alloc((size_t)N_d * 4);
    int*   off2   = (int*)alloc((size_t)(N_d + 1) * 4);
    int*   cur2   = (int*)alloc((size_t)N_d * 4);
    int*   srcs2  = (int*)alloc((size_t)E * 4);
    float* sigw   = (float*)alloc((size_t)N_e * 4);
    unsigned short* BfragB = (unsigned short*)alloc((size_t)32768 * 2);  // phase B weights
    unsigned short* BfragD = (unsigned short*)alloc((size_t)32768 * 2);  // phase D weights

    int prepN = (N_e > N_d) ? N_e : N_d;
    prep_kernel<<<(prepN + 255) / 256, 256, 0, stream>>>(ew, sigw, cnt1, cnt2, N_e, N_d);
    wfrag_kernel<<<128, 256, 0, stream>>>(W_e_self, W_d2e, BfragB);
    wfrag_kernel<<<128, 256, 0, stream>>>(W_d_self, W_e2d, BfragD);
    hist_kernel<<<(E + 255) / 256, 256, 0, stream>>>(e_d2e, e_e2d, cnt1, cnt2, E);
    scan_kernel<<<2, 256, 0, stream>>>(cnt1, off1, cur1, N_e, cnt2, off2, cur2, N_d);
    fill_kernel<<<(E + 255) / 256, 256, 0, stream>>>(e_d2e, e_e2d, cur1, srcs1, cur2, srcs2, E);

    // Phase B: E-node update (gathers hD via CSR1, sigmoid weights)
    int rowsB = Bsz * N_e;
    int shB = __builtin_ctz(N_e);
    node_update_kernel<<<(rowsB + ROWS - 1) / ROWS, 256, 0, stream>>>(
        hE, hD, off1, srcs1, sigw, BfragB, b_e, g_e, beta_e, outE,
        shB, N_e - 1, (long)N_d * H, rowsB);

    // Phase D: D-node update (gathers hE_new from d_out via CSR2)
    int rowsD = Bsz * N_d;
    int shD = __builtin_ctz(N_d);
    node_update_kernel<<<(rowsD + ROWS - 1) / ROWS, 256, 0, stream>>>(
        hD, outE, off2, srcs2, nullptr, BfragD, b_d, g_d, beta_d, outD,
        shD, N_d - 1, (long)N_e * H, rowsD);
}

// Round 4
// 579.422 us; speedup vs baseline: 1.2173x; 1.0024x over previous
//
#include <hip/hip_runtime.h>
#include <math.h>

#define H 128
#define ROWS 32          // rows per node_update block (32 consecutive n, one b)
#define ASTRIDE 264      // bf16 elems per row in Abuf (256 + 8 pad)
#define XSTRIDE 132      // fp32 elems per row in aliased XN view (264*2B == 132*4B)
#define IDXCAP 512       // LDS-staged CSR srcs per block (avg 128/256; global fallback past cap)

typedef __attribute__((ext_vector_type(8))) short short8;
typedef __attribute__((ext_vector_type(4))) float floatx4;
typedef __attribute__((ext_vector_type(4))) unsigned short ushortx4;

__device__ __forceinline__ unsigned short f2bf(float f) {
    unsigned int u = __float_as_uint(f);
    u += 0x7FFFu + ((u >> 16) & 1u);       // round-to-nearest-even
    return (unsigned short)(u >> 16);
}

// ---------------- prep: sigmoid(ew), zero counters ----------------
__global__ void prep_kernel(const float* __restrict__ ew, float* __restrict__ sigw,
                            int* __restrict__ cnt1, int* __restrict__ cnt2,
                            int N_e, int N_d) {
    int i = blockIdx.x * blockDim.x + threadIdx.x;
    if (i < N_e) { sigw[i] = 1.0f / (1.0f + expf(-ew[i])); cnt1[i] = 0; }
    if (i < N_d) cnt2[i] = 0;
}

// ---------------- prep: bf16 B-operand fragments for MFMA ----------------
// Bfrag[t][kk][lane][j] = Wcat[k = kk*32 + (lane>>4)*8 + j][n = t*16 + (lane&15)]
// where Wcat[k][n] = (k<128 ? Wself[n][k] : Wmsg[n][k-128])   (y = x @ W.T)
__global__ void wfrag_kernel(const float* __restrict__ Wself,
                             const float* __restrict__ Wmsg,
                             unsigned short* __restrict__ Bfrag) {
    int idx = blockIdx.x * blockDim.x + threadIdx.x;   // 0..32767
    int j    = idx & 7;
    int lane = (idx >> 3) & 63;
    int kk   = (idx >> 9) & 7;
    int t    = idx >> 12;
    int k = kk * 32 + ((lane >> 4) << 3) + j;
    int n = (t << 4) + (lane & 15);
    float w = (k < H) ? Wself[n * H + k] : Wmsg[n * H + (k - H)];
    Bfrag[idx] = f2bf(w);
}

// ---------------- CSR build ----------------
__global__ void hist_kernel(const int* __restrict__ e_d2e, const int* __restrict__ e_e2d,
                            int* __restrict__ cnt1, int* __restrict__ cnt2, int E) {
    int e = blockIdx.x * blockDim.x + threadIdx.x;
    if (e < E) {
        atomicAdd(&cnt1[e_d2e[E + e]], 1);
        atomicAdd(&cnt2[e_e2d[E + e]], 1);
    }
}

__global__ void scan_kernel(const int* __restrict__ cnt1, int* __restrict__ off1,
                            int* __restrict__ cur1, int N1,
                            const int* __restrict__ cnt2, int* __restrict__ off2,
                            int* __restrict__ cur2, int N2) {
    const int* cnt = blockIdx.x ? cnt2 : cnt1;
    int* off = blockIdx.x ? off2 : off1;
    int* cur = blockIdx.x ? cur2 : cur1;
    int N    = blockIdx.x ? N2 : N1;
    __shared__ int part[257];
    int tid = threadIdx.x;
    int chunk = (N + 255) / 256;
    int lo = tid * chunk, hi = min(lo + chunk, N);
    int s = 0;
    for (int i = lo; i < hi; ++i) s += cnt[i];
    part[tid] = s;
    __syncthreads();
    if (tid == 0) {
        int run = 0;
        for (int i = 0; i < 256; ++i) { int t = part[i]; part[i] = run; run += t; }
        part[256] = run;
    }
    __syncthreads();
    int run = part[tid];
    for (int i = lo; i < hi; ++i) { off[i] = run; cur[i] = run; run += cnt[i]; }
    if (tid == 0) off[N] = part[256];
}

__global__ void fill_kernel(const int* __restrict__ e_d2e, const int* __restrict__ e_e2d,
                            int* __restrict__ cur1, int* __restrict__ srcs1,
                            int* __restrict__ cur2, int* __restrict__ srcs2, int E) {
    int e = blockIdx.x * blockDim.x + threadIdx.x;
    if (e < E) {
        int p1 = atomicAdd(&cur1[e_d2e[E + e]], 1); srcs1[p1] = e_d2e[e];
        int p2 = atomicAdd(&cur2[e_e2d[E + e]], 1); srcs2[p2] = e_e2d[e];
    }
}

// ---------------- fused node update (MFMA + LDS-staged CSR) ----------------
// Block: 32 rows x 128 outputs. GEMM [32 x 256(K)] @ [256 x 128],
// A = [x_bf16 | S_bf16], B = [Wself^T; Wmsg^T] pre-fragmentized.
// Wave w owns n-tiles {2w, 2w+1}; m-tiles 0..1.
// Stage: float4 gather, idx-reads software-pipelined one batch ahead so the
// LDS latency hides under the gather vmcnt wait. Epilogue x re-read is
// prefetched into registers before the MFMA loop (hidden under MFMA).
// 19456 B LDS x 8 blocks = 155.6 KB < 160 KB -> 8 blocks/CU at <=64 VGPR.
__global__ __launch_bounds__(256, 8)
void node_update_kernel(const float* __restrict__ x,
                        const float* __restrict__ gsrc,
                        const int* __restrict__ off,
                        const int* __restrict__ srcs,
                        const float* __restrict__ sigw,     // null for phase D
                        const unsigned short* __restrict__ Bfrag,
                        const float* __restrict__ bias,
                        const float* __restrict__ gamma,
                        const float* __restrict__ beta,
                        float* __restrict__ out,
                        int nShift, int nMask, long gStride, int nrows) {
    __shared__ __align__(16) unsigned short Abuf[ROWS * ASTRIDE];
    __shared__ int idxbuf[IDXCAP];
    __shared__ int offs[ROWS + 1];
    float* XN = reinterpret_cast<float*>(Abuf);   // aliased: reused after MFMA

    const int tid  = threadIdx.x;
    const int row0 = blockIdx.x * ROWS;
    const int n0   = row0 & nMask;     // rows are 32 consecutive n of one b (N % 32 == 0)

    // ---- stage CSR offsets + source indices into LDS ----
    if (tid <= ROWS) offs[tid] = off[n0 + tid];
    __syncthreads();
    const int jbase = offs[0];
    const int jtot  = offs[ROWS] - jbase;
    const int jlds  = min(jtot, IDXCAP);
    for (int j = tid; j < jlds; j += 256) idxbuf[j] = srcs[jbase + j];
    __syncthreads();

    // ---- stage: x -> bf16, scaled gather-sum -> bf16 (float4 per lane) ----
    {
        const int l32 = tid & 31;          // 32 lanes cover a 128-col row, 4 cols each
        const int sub = tid >> 5;          // 0..7: row within pass
        const int c0  = l32 * 4;
        const float* gb = gsrc + (size_t)(row0 >> nShift) * gStride;
        const bool allLds = (jtot <= IDXCAP);
#pragma unroll
        for (int pass = 0; pass < 4; ++pass) {
            const int r  = pass * 8 + sub;
            const int rg = row0 + r;
            floatx4 xv = {0.f, 0.f, 0.f, 0.f};
            floatx4 sv = {0.f, 0.f, 0.f, 0.f};
            if (rg < nrows) {
                xv = *reinterpret_cast<const floatx4*>(&x[(size_t)rg * H + c0]);
                const int beg = offs[r] - jbase, end = offs[r + 1] - jbase;
                int j = beg;
                if (allLds) {
                    // pipelined: idx batch for round k+1 is read while round k's
                    // gathers are outstanding (lgkm hides under vmcnt)
                    int s0, s1, s2, s3;
                    bool have4 = (j + 4 <= end);
                    if (have4) {
                        s0 = idxbuf[j]; s1 = idxbuf[j + 1];
                        s2 = idxbuf[j + 2]; s3 = idxbuf[j + 3];
                    }
                    while (have4) {
                        floatx4 v0 = *reinterpret_cast<const floatx4*>(&gb[(size_t)s0 * H + c0]);
                        floatx4 v1 = *reinterpret_cast<const floatx4*>(&gb[(size_t)s1 * H + c0]);
                        floatx4 v2 = *reinterpret_cast<const floatx4*>(&gb[(size_t)s2 * H + c0]);
                        floatx4 v3 = *reinterpret_cast<const floatx4*>(&gb[(size_t)s3 * H + c0]);
                        j += 4;
                        have4 = (j + 4 <= end);
                        if (have4) {
                            s0 = idxbuf[j]; s1 = idxbuf[j + 1];
                            s2 = idxbuf[j + 2]; s3 = idxbuf[j + 3];
                        }
                        sv += (v0 + v1) + (v2 + v3);
                    }
                    for (; j < end; ++j) {
                        int s = idxbuf[j];
                        sv += *reinterpret_cast<const floatx4*>(&gb[(size_t)s * H + c0]);
                    }
                } else {
                    for (; j < end; ++j) {   // rare: block with >IDXCAP edges
                        int s = (j < IDXCAP) ? idxbuf[j] : srcs[jbase + j];
                        sv += *reinterpret_cast<const floatx4*>(&gb[(size_t)s * H + c0]);
                    }
                }
                float scale = (sigw ? sigw[n0 + r] : 1.0f) / fmaxf((float)(end - beg), 1.0f);
                sv *= scale;
            }
            ushortx4 xb, sb;
#pragma unroll
            for (int q = 0; q < 4; ++q) { xb[q] = f2bf(xv[q]); sb[q] = f2bf(sv[q]); }
            *reinterpret_cast<ushortx4*>(&Abuf[r * ASTRIDE + c0])     = xb;
            *reinterpret_cast<ushortx4*>(&Abuf[r * ASTRIDE + H + c0]) = sb;
        }
    }
    __syncthreads();

    const int wave = tid >> 6, lane = tid & 63;
    const int quad = lane >> 4, l16 = lane & 15;

    // ---- prefetch epilogue residual x into registers (lands under MFMA) ----
    float xpre[2][2][4];
#pragma unroll
    for (int mt = 0; mt < 2; ++mt)
#pragma unroll
        for (int t = 0; t < 2; ++t)
#pragma unroll
            for (int reg = 0; reg < 4; ++reg) {
                int r  = 16 * mt + quad * 4 + reg;
                int rg = row0 + r;
                int col = 32 * wave + 16 * t + l16;
                xpre[mt][t][reg] = (rg < nrows) ? x[(size_t)rg * H + col] : 0.f;
            }

    floatx4 acc[2][2];
#pragma unroll
    for (int mt = 0; mt < 2; ++mt)
#pragma unroll
        for (int t = 0; t < 2; ++t)
            acc[mt][t] = (floatx4){0.f, 0.f, 0.f, 0.f};

    // ---- MFMA main loop: K = 256 in 8 chunks of 32 ----
    const unsigned short* bf_base = Bfrag + (size_t)(2 * wave) * 4096;  // t stride = 8*64*8
    for (int kk = 0; kk < 8; ++kk) {
        const short8 b0 = *reinterpret_cast<const short8*>(bf_base + (kk * 64 + lane) * 8);
        const short8 b1 = *reinterpret_cast<const short8*>(bf_base + 4096 + (kk * 64 + lane) * 8);
#pragma unroll
        for (int mt = 0; mt < 2; ++mt) {
            const short8 a = *reinterpret_cast<const short8*>(
                &Abuf[(16 * mt + l16) * ASTRIDE + kk * 32 + quad * 8]);
            acc[mt][0] = __builtin_amdgcn_mfma_f32_16x16x32_bf16(a, b0, acc[mt][0], 0, 0, 0);
            acc[mt][1] = __builtin_amdgcn_mfma_f32_16x16x32_bf16(a, b1, acc[mt][1], 0, 0, 0);
        }
    }
    __syncthreads();   // all Abuf reads complete before XN overwrite

    // ---- epilogue 1: bias + ReLU + fp32 residual (prefetched x) -> XN ----
#pragma unroll
    for (int t = 0; t < 2; ++t) {
        int col = 32 * wave + 16 * t + l16;
        float bb = bias[col];
#pragma unroll
        for (int mt = 0; mt < 2; ++mt) {
#pragma unroll
            for (int reg = 0; reg < 4; ++reg) {
                int r  = 16 * mt + quad * 4 + reg;   // C/D: row = quad*4+reg, col = lane&15
                float pre = fmaxf(acc[mt][t][reg] + bb, 0.f);
                float xn  = xpre[mt][t][reg] + pre;
                XN[r * XSTRIDE + col] = xn;
            }
        }
    }
    __syncthreads();

    // ---- epilogue 2: LayerNorm (wave handles 8 rows; lane -> cols {lane, lane+64}) ----
    {
        const int o0 = lane, o1 = lane + 64;
        const float g0 = gamma[o0], g1 = gamma[o1];
        const float be0 = beta[o0], be1 = beta[o1];
        for (int rr = 0; rr < 8; ++rr) {
            int r  = 8 * wave + rr;
            int rg = row0 + r;
            if (rg >= nrows) break;
            float xn0 = XN[r * XSTRIDE + o0];
            float xn1 = XN[r * XSTRIDE + o1];
            float s  = xn0 + xn1;
            float s2 = xn0 * xn0 + xn1 * xn1;
#pragma unroll
            for (int m = 32; m >= 1; m >>= 1) {
                s  += __shfl_xor(s, m, 64);
                s2 += __shfl_xor(s2, m, 64);
            }
            float mean = s * (1.0f / H);
            float var  = s2 * (1.0f / H) - mean * mean;
            float rstd = rsqrtf(var + 1e-5f);
            out[(size_t)rg * H + o0] = (xn0 - mean) * rstd * g0 + be0;
            out[(size_t)rg * H + o1] = (xn1 - mean) * rstd * g1 + be1;
        }
    }
}

extern "C" void kernel_launch(void* const* d_in, const int* in_sizes, int n_in,
                              void* d_out, int out_size, void* d_ws, size_t ws_size,
                              hipStream_t stream) {
    const float* hD       = (const float*)d_in[0];
    const float* hE       = (const float*)d_in[1];
    const int*   e_d2e    = (const int*)d_in[2];
    const int*   e_e2d    = (const int*)d_in[3];
    const float* ew       = (const float*)d_in[4];
    const float* W_d2e    = (const float*)d_in[5];
    const float* W_e_self = (const float*)d_in[6];
    const float* b_e      = (const float*)d_in[7];
    const float* g_e      = (const float*)d_in[8];
    const float* beta_e   = (const float*)d_in[9];
    const float* W_e2d    = (const float*)d_in[10];
    const float* W_d_self = (const float*)d_in[11];
    const float* b_d      = (const float*)d_in[12];
    const float* g_d      = (const float*)d_in[13];
    const float* beta_d   = (const float*)d_in[14];

    const int E   = in_sizes[2] / 2;
    const int N_e = in_sizes[4];
    const int Bsz = in_sizes[1] / (N_e * H);
    const int N_d = in_sizes[0] / (Bsz * H);

    float* outD = (float*)d_out;
    float* outE = (float*)d_out + (size_t)Bsz * N_d * H;

    char* p = (char*)d_ws;
    auto alloc = [&](size_t bytes) { char* r = p; p += (bytes + 255) & ~(size_t)255; return r; };
    int*   cnt1   = (int*)alloc((size_t)N_e * 4);
    int*   off1   = (int*)alloc((size_t)(N_e + 1) * 4);
    int*   cur1   = (int*)alloc((size_t)N_e * 4);
    int*   srcs1  = (int*)alloc((size_t)E * 4);
    int*   cnt2   = (int*)alloc((size_t)N_d * 4);
    int*   off2   = (int*)alloc((size_t)(N_d + 1) * 4);
    int*   cur2   = (int*)alloc((size_t)N_d * 4);
    int*   srcs2  = (int*)alloc((size_t)E * 4);
    float* sigw   = (float*)alloc((size_t)N_e * 4);
    unsigned short* BfragB = (unsigned short*)alloc((size_t)32768 * 2);  // phase B weights
    unsigned short* BfragD = (unsigned short*)alloc((size_t)32768 * 2);  // phase D weights

    int prepN = (N_e > N_d) ? N_e : N_d;
    prep_kernel<<<(prepN + 255) / 256, 256, 0, stream>>>(ew, sigw, cnt1, cnt2, N_e, N_d);
    wfrag_kernel<<<128, 256, 0, stream>>>(W_e_self, W_d2e, BfragB);
    wfrag_kernel<<<128, 256, 0, stream>>>(W_d_self, W_e2d, BfragD);
    hist_kernel<<<(E + 255) / 256, 256, 0, stream>>>(e_d2e, e_e2d, cnt1, cnt2, E);
    scan_kernel<<<2, 256, 0, stream>>>(cnt1, off1, cur1, N_e, cnt2, off2, cur2, N_d);
    fill_kernel<<<(E + 255) / 256, 256, 0, stream>>>(e_d2e, e_e2d, cur1, srcs1, cur2, srcs2, E);

    // Phase B: E-node update (gathers hD via CSR1, sigmoid weights)
    int rowsB = Bsz * N_e;
    int shB = __builtin_ctz(N_e);
    node_update_kernel<<<(rowsB + ROWS - 1) / ROWS, 256, 0, stream>>>(
        hE, hD, off1, srcs1, sigw, BfragB, b_e, g_e, beta_e, outE,
        shB, N_e - 1, (long)N_d * H, rowsB);

    // Phase D: D-node update (gathers hE_new from d_out via CSR2)
    int rowsD = Bsz * N_d;
    int shD = __builtin_ctz(N_d);
    node_update_kernel<<<(rowsD + ROWS - 1) / ROWS, 256, 0, stream>>>(
        hD, outE, off2, srcs2, nullptr, BfragD, b_d, g_d, beta_d, outD,
        shD, N_d - 1, (long)N_e * H, rowsD);
}

// Round 5
// 570.614 us; speedup vs baseline: 1.2361x; 1.0154x over previous
//
#include <hip/hip_runtime.h>
#include <math.h>

#define H 128
#define ROWS 32          // rows per node_update block (32 consecutive n, one b)
#define ASTRIDE 264      // bf16 elems per row in Abuf (256 + 8 pad)
#define XSTRIDE 132      // fp32 elems per row in aliased XN view (264*2B == 132*4B)
#define IDXCAP 512       // LDS-staged CSR srcs per block (avg 128/256; global fallback past cap)

typedef __attribute__((ext_vector_type(8))) short short8;
typedef __attribute__((ext_vector_type(4))) float floatx4;
typedef __attribute__((ext_vector_type(4))) unsigned short ushortx4;

__device__ __forceinline__ unsigned short f2bf(float f) {
    unsigned int u = __float_as_uint(f);
    u += 0x7FFFu + ((u >> 16) & 1u);       // round-to-nearest-even
    return (unsigned short)(u >> 16);
}

// ---------------- prep: sigmoid(ew), zero counters ----------------
__global__ void prep_kernel(const float* __restrict__ ew, float* __restrict__ sigw,
                            int* __restrict__ cnt1, int* __restrict__ cnt2,
                            int N_e, int N_d) {
    int i = blockIdx.x * blockDim.x + threadIdx.x;
    if (i < N_e) { sigw[i] = 1.0f / (1.0f + expf(-ew[i])); cnt1[i] = 0; }
    if (i < N_d) cnt2[i] = 0;
}

// ---------------- prep: bf16 B-operand fragments for MFMA ----------------
// Bfrag[t][kk][lane][j] = Wcat[k = kk*32 + (lane>>4)*8 + j][n = t*16 + (lane&15)]
// where Wcat[k][n] = (k<128 ? Wself[n][k] : Wmsg[n][k-128])   (y = x @ W.T)
__global__ void wfrag_kernel(const float* __restrict__ Wself,
                             const float* __restrict__ Wmsg,
                             unsigned short* __restrict__ Bfrag) {
    int idx = blockIdx.x * blockDim.x + threadIdx.x;   // 0..32767
    int j    = idx & 7;
    int lane = (idx >> 3) & 63;
    int kk   = (idx >> 9) & 7;
    int t    = idx >> 12;
    int k = kk * 32 + ((lane >> 4) << 3) + j;
    int n = (t << 4) + (lane & 15);
    float w = (k < H) ? Wself[n * H + k] : Wmsg[n * H + (k - H)];
    Bfrag[idx] = f2bf(w);
}

// ---------------- CSR build ----------------
__global__ void hist_kernel(const int* __restrict__ e_d2e, const int* __restrict__ e_e2d,
                            int* __restrict__ cnt1, int* __restrict__ cnt2, int E) {
    int e = blockIdx.x * blockDim.x + threadIdx.x;
    if (e < E) {
        atomicAdd(&cnt1[e_d2e[E + e]], 1);
        atomicAdd(&cnt2[e_e2d[E + e]], 1);
    }
}

__global__ void scan_kernel(const int* __restrict__ cnt1, int* __restrict__ off1,
                            int* __restrict__ cur1, int N1,
                            const int* __restrict__ cnt2, int* __restrict__ off2,
                            int* __restrict__ cur2, int N2) {
    const int* cnt = blockIdx.x ? cnt2 : cnt1;
    int* off = blockIdx.x ? off2 : off1;
    int* cur = blockIdx.x ? cur2 : cur1;
    int N    = blockIdx.x ? N2 : N1;
    __shared__ int part[257];
    int tid = threadIdx.x;
    int chunk = (N + 255) / 256;
    int lo = tid * chunk, hi = min(lo + chunk, N);
    int s = 0;
    for (int i = lo; i < hi; ++i) s += cnt[i];
    part[tid] = s;
    __syncthreads();
    if (tid == 0) {
        int run = 0;
        for (int i = 0; i < 256; ++i) { int t = part[i]; part[i] = run; run += t; }
        part[256] = run;
    }
    __syncthreads();
    int run = part[tid];
    for (int i = lo; i < hi; ++i) { off[i] = run; cur[i] = run; run += cnt[i]; }
    if (tid == 0) off[N] = part[256];
}

__global__ void fill_kernel(const int* __restrict__ e_d2e, const int* __restrict__ e_e2d,
                            int* __restrict__ cur1, int* __restrict__ srcs1,
                            int* __restrict__ cur2, int* __restrict__ srcs2, int E) {
    int e = blockIdx.x * blockDim.x + threadIdx.x;
    if (e < E) {
        int p1 = atomicAdd(&cur1[e_d2e[E + e]], 1); srcs1[p1] = e_d2e[e];
        int p2 = atomicAdd(&cur2[e_e2d[E + e]], 1); srcs2[p2] = e_e2d[e];
    }
}

// ---------------- fused node update (MFMA + LDS-staged CSR) ----------------
// Block: 32 rows x 128 outputs. GEMM [32 x 256(K)] @ [256 x 128],
// A = [x_bf16 | S_bf16], B = [Wself^T; Wmsg^T] pre-fragmentized.
// XCD batch-affinity swizzle: HW dispatches wg i -> XCD i%8; remapping
// wg = (bid&7)*(nwg/8) + (bid>>3) gives each XCD a contiguous chunk =
// exactly 2 batches, so its gathers touch an 8MB (B) / 16MB (D) slice
// instead of the full 64/128MB -> L2-local gathers (~200cy vs ~600cy L3).
__global__ __launch_bounds__(256, 8)
void node_update_kernel(const float* __restrict__ x,
                        const float* __restrict__ gsrc,
                        const int* __restrict__ off,
                        const int* __restrict__ srcs,
                        const float* __restrict__ sigw,     // null for phase D
                        const unsigned short* __restrict__ Bfrag,
                        const float* __restrict__ bias,
                        const float* __restrict__ gamma,
                        const float* __restrict__ beta,
                        float* __restrict__ out,
                        int nShift, int nMask, long gStride, int nrows) {
    __shared__ __align__(16) unsigned short Abuf[ROWS * ASTRIDE];
    __shared__ int idxbuf[IDXCAP];
    __shared__ int offs[ROWS + 1];
    float* XN = reinterpret_cast<float*>(Abuf);   // aliased: reused after MFMA

    const int tid  = threadIdx.x;
    // ---- XCD batch-affinity swizzle (bijective when gridDim.x % 8 == 0) ----
    int wg;
    {
        const int nwg = gridDim.x;
        const int bid = blockIdx.x;
        wg = ((nwg & 7) == 0) ? ((bid & 7) * (nwg >> 3) + (bid >> 3)) : bid;
    }
    const int row0 = wg * ROWS;
    const int n0   = row0 & nMask;     // rows are 32 consecutive n of one b (N % 32 == 0)

    // ---- stage CSR offsets + source indices into LDS ----
    if (tid <= ROWS) offs[tid] = off[n0 + tid];
    __syncthreads();
    const int jbase = offs[0];
    const int jtot  = offs[ROWS] - jbase;
    const int jlds  = min(jtot, IDXCAP);
    for (int j = tid; j < jlds; j += 256) idxbuf[j] = srcs[jbase + j];
    __syncthreads();

    // ---- stage: x -> bf16, scaled gather-sum -> bf16 (float4 per lane) ----
    {
        const int l32 = tid & 31;          // 32 lanes cover a 128-col row, 4 cols each
        const int sub = tid >> 5;          // 0..7: row within pass
        const int c0  = l32 * 4;
        const float* gb = gsrc + (size_t)(row0 >> nShift) * gStride;
        const bool allLds = (jtot <= IDXCAP);
#pragma unroll
        for (int pass = 0; pass < 4; ++pass) {
            const int r  = pass * 8 + sub;
            const int rg = row0 + r;
            floatx4 xv = {0.f, 0.f, 0.f, 0.f};
            floatx4 sv = {0.f, 0.f, 0.f, 0.f};
            if (rg < nrows) {
                xv = *reinterpret_cast<const floatx4*>(&x[(size_t)rg * H + c0]);
                const int beg = offs[r] - jbase, end = offs[r + 1] - jbase;
                int j = beg;
                if (allLds) {
                    // pipelined: idx batch for round k+1 is read while round k's
                    // gathers are outstanding (lgkm hides under vmcnt)
                    int s0, s1, s2, s3;
                    bool have4 = (j + 4 <= end);
                    if (have4) {
                        s0 = idxbuf[j]; s1 = idxbuf[j + 1];
                        s2 = idxbuf[j + 2]; s3 = idxbuf[j + 3];
                    }
                    while (have4) {
                        floatx4 v0 = *reinterpret_cast<const floatx4*>(&gb[(size_t)s0 * H + c0]);
                        floatx4 v1 = *reinterpret_cast<const floatx4*>(&gb[(size_t)s1 * H + c0]);
                        floatx4 v2 = *reinterpret_cast<const floatx4*>(&gb[(size_t)s2 * H + c0]);
                        floatx4 v3 = *reinterpret_cast<const floatx4*>(&gb[(size_t)s3 * H + c0]);
                        j += 4;
                        have4 = (j + 4 <= end);
                        if (have4) {
                            s0 = idxbuf[j]; s1 = idxbuf[j + 1];
                            s2 = idxbuf[j + 2]; s3 = idxbuf[j + 3];
                        }
                        sv += (v0 + v1) + (v2 + v3);
                    }
                    for (; j < end; ++j) {
                        int s = idxbuf[j];
                        sv += *reinterpret_cast<const floatx4*>(&gb[(size_t)s * H + c0]);
                    }
                } else {
                    for (; j < end; ++j) {   // rare: block with >IDXCAP edges
                        int s = (j < IDXCAP) ? idxbuf[j] : srcs[jbase + j];
                        sv += *reinterpret_cast<const floatx4*>(&gb[(size_t)s * H + c0]);
                    }
                }
                float scale = (sigw ? sigw[n0 + r] : 1.0f) / fmaxf((float)(end - beg), 1.0f);
                sv *= scale;
            }
            ushortx4 xb, sb;
#pragma unroll
            for (int q = 0; q < 4; ++q) { xb[q] = f2bf(xv[q]); sb[q] = f2bf(sv[q]); }
            *reinterpret_cast<ushortx4*>(&Abuf[r * ASTRIDE + c0])     = xb;
            *reinterpret_cast<ushortx4*>(&Abuf[r * ASTRIDE + H + c0]) = sb;
        }
    }
    __syncthreads();

    const int wave = tid >> 6, lane = tid & 63;
    const int quad = lane >> 4, l16 = lane & 15;

    // ---- prefetch epilogue residual x into registers (lands under MFMA) ----
    float xpre[2][2][4];
#pragma unroll
    for (int mt = 0; mt < 2; ++mt)
#pragma unroll
        for (int t = 0; t < 2; ++t)
#pragma unroll
            for (int reg = 0; reg < 4; ++reg) {
                int r  = 16 * mt + quad * 4 + reg;
                int rg = row0 + r;
                int col = 32 * wave + 16 * t + l16;
                xpre[mt][t][reg] = (rg < nrows) ? x[(size_t)rg * H + col] : 0.f;
            }

    floatx4 acc[2][2];
#pragma unroll
    for (int mt = 0; mt < 2; ++mt)
#pragma unroll
        for (int t = 0; t < 2; ++t)
            acc[mt][t] = (floatx4){0.f, 0.f, 0.f, 0.f};

    // ---- MFMA main loop: K = 256 in 8 chunks of 32 ----
    const unsigned short* bf_base = Bfrag + (size_t)(2 * wave) * 4096;  // t stride = 8*64*8
    for (int kk = 0; kk < 8; ++kk) {
        const short8 b0 = *reinterpret_cast<const short8*>(bf_base + (kk * 64 + lane) * 8);
        const short8 b1 = *reinterpret_cast<const short8*>(bf_base + 4096 + (kk * 64 + lane) * 8);
#pragma unroll
        for (int mt = 0; mt < 2; ++mt) {
            const short8 a = *reinterpret_cast<const short8*>(
                &Abuf[(16 * mt + l16) * ASTRIDE + kk * 32 + quad * 8]);
            acc[mt][0] = __builtin_amdgcn_mfma_f32_16x16x32_bf16(a, b0, acc[mt][0], 0, 0, 0);
            acc[mt][1] = __builtin_amdgcn_mfma_f32_16x16x32_bf16(a, b1, acc[mt][1], 0, 0, 0);
        }
    }
    __syncthreads();   // all Abuf reads complete before XN overwrite

    // ---- epilogue 1: bias + ReLU + fp32 residual (prefetched x) -> XN ----
#pragma unroll
    for (int t = 0; t < 2; ++t) {
        int col = 32 * wave + 16 * t + l16;
        float bb = bias[col];
#pragma unroll
        for (int mt = 0; mt < 2; ++mt) {
#pragma unroll
            for (int reg = 0; reg < 4; ++reg) {
                int r  = 16 * mt + quad * 4 + reg;   // C/D: row = quad*4+reg, col = lane&15
                float pre = fmaxf(acc[mt][t][reg] + bb, 0.f);
                float xn  = xpre[mt][t][reg] + pre;
                XN[r * XSTRIDE + col] = xn;
            }
        }
    }
    __syncthreads();

    // ---- epilogue 2: LayerNorm (wave handles 8 rows; lane -> cols {lane, lane+64}) ----
    {
        const int o0 = lane, o1 = lane + 64;
        const float g0 = gamma[o0], g1 = gamma[o1];
        const float be0 = beta[o0], be1 = beta[o1];
        for (int rr = 0; rr < 8; ++rr) {
            int r  = 8 * wave + rr;
            int rg = row0 + r;
            if (rg >= nrows) break;
            float xn0 = XN[r * XSTRIDE + o0];
            float xn1 = XN[r * XSTRIDE + o1];
            float s  = xn0 + xn1;
            float s2 = xn0 * xn0 + xn1 * xn1;
#pragma unroll
            for (int m = 32; m >= 1; m >>= 1) {
                s  += __shfl_xor(s, m, 64);
                s2 += __shfl_xor(s2, m, 64);
            }
            float mean = s * (1.0f / H);
            float var  = s2 * (1.0f / H) - mean * mean;
            float rstd = rsqrtf(var + 1e-5f);
            out[(size_t)rg * H + o0] = (xn0 - mean) * rstd * g0 + be0;
            out[(size_t)rg * H + o1] = (xn1 - mean) * rstd * g1 + be1;
        }
    }
}

extern "C" void kernel_launch(void* const* d_in, const int* in_sizes, int n_in,
                              void* d_out, int out_size, void* d_ws, size_t ws_size,
                              hipStream_t stream) {
    const float* hD       = (const float*)d_in[0];
    const float* hE       = (const float*)d_in[1];
    const int*   e_d2e    = (const int*)d_in[2];
    const int*   e_e2d    = (const int*)d_in[3];
    const float* ew       = (const float*)d_in[4];
    const float* W_d2e    = (const float*)d_in[5];
    const float* W_e_self = (const float*)d_in[6];
    const float* b_e      = (const float*)d_in[7];
    const float* g_e      = (const float*)d_in[8];
    const float* beta_e   = (const float*)d_in[9];
    const float* W_e2d    = (const float*)d_in[10];
    const float* W_d_self = (const float*)d_in[11];
    const float* b_d      = (const float*)d_in[12];
    const float* g_d      = (const float*)d_in[13];
    const float* beta_d   = (const float*)d_in[14];

    const int E   = in_sizes[2] / 2;
    const int N_e = in_sizes[4];
    const int Bsz = in_sizes[1] / (N_e * H);
    const int N_d = in_sizes[0] / (Bsz * H);

    float* outD = (float*)d_out;
    float* outE = (float*)d_out + (size_t)Bsz * N_d * H;

    char* p = (char*)d_ws;
    auto alloc = [&](size_t bytes) { char* r = p; p += (bytes + 255) & ~(size_t)255; return r; };
    int*   cnt1   = (int*)alloc((size_t)N_e * 4);
    int*   off1   = (int*)alloc((size_t)(N_e + 1) * 4);
    int*   cur1   = (int*)alloc((size_t)N_e * 4);
    int*   srcs1  = (int*)alloc((size_t)E * 4);
    int*   cnt2   = (int*)alloc((size_t)N_d * 4);
    int*   off2   = (int*)alloc((size_t)(N_d + 1) * 4);
    int*   cur2   = (int*)alloc((size_t)N_d * 4);
    int*   srcs2  = (int*)alloc((size_t)E * 4);
    float* sigw   = (float*)alloc((size_t)N_e * 4);
    unsigned short* BfragB = (unsigned short*)alloc((size_t)32768 * 2);  // phase B weights
    unsigned short* BfragD = (unsigned short*)alloc((size_t)32768 * 2);  // phase D weights

    int prepN = (N_e > N_d) ? N_e : N_d;
    prep_kernel<<<(prepN + 255) / 256, 256, 0, stream>>>(ew, sigw, cnt1, cnt2, N_e, N_d);
    wfrag_kernel<<<128, 256, 0, stream>>>(W_e_self, W_d2e, BfragB);
    wfrag_kernel<<<128, 256, 0, stream>>>(W_d_self, W_e2d, BfragD);
    hist_kernel<<<(E + 255) / 256, 256, 0, stream>>>(e_d2e, e_e2d, cnt1, cnt2, E);
    scan_kernel<<<2, 256, 0, stream>>>(cnt1, off1, cur1, N_e, cnt2, off2, cur2, N_d);
    fill_kernel<<<(E + 255) / 256, 256, 0, stream>>>(e_d2e, e_e2d, cur1, srcs1, cur2, srcs2, E);

    // Phase B: E-node update (gathers hD via CSR1, sigmoid weights)
    int rowsB = Bsz * N_e;
    int shB = __builtin_ctz(N_e);
    node_update_kernel<<<(rowsB + ROWS - 1) / ROWS, 256, 0, stream>>>(
        hE, hD, off1, srcs1, sigw, BfragB, b_e, g_e, beta_e, outE,
        shB, N_e - 1, (long)N_d * H, rowsB);

    // Phase D: D-node update (gathers hE_new from d_out via CSR2)
    int rowsD = Bsz * N_d;
    int shD = __builtin_ctz(N_d);
    node_update_kernel<<<(rowsD + ROWS - 1) / ROWS, 256, 0, stream>>>(
        hD, outE, off2, srcs2, nullptr, BfragD, b_d, g_d, beta_d, outD,
        shD, N_d - 1, (long)N_e * H, rowsD);
}

// Round 6
// 569.793 us; speedup vs baseline: 1.2379x; 1.0014x over previous
//
#include <hip/hip_runtime.h>
#include <math.h>

#define H 128
#define ROWS 32          // rows per node_update block (32 consecutive n, one b)
#define ASTRIDE 264      // bf16 elems per row in Abuf (256 + 8 pad)
#define XSTRIDE 132      // fp32 elems per row in aliased XN view (264*2B == 132*4B)
#define IDXCAP 512       // LDS-staged CSR srcs per block (avg 128/256; global fallback past cap)

typedef __attribute__((ext_vector_type(8))) short short8;
typedef __attribute__((ext_vector_type(4))) float floatx4;
typedef __attribute__((ext_vector_type(4))) unsigned short ushortx4;

__device__ __forceinline__ unsigned short f2bf(float f) {
    unsigned int u = __float_as_uint(f);
    u += 0x7FFFu + ((u >> 16) & 1u);       // round-to-nearest-even
    return (unsigned short)(u >> 16);
}

// ---------------- prep: sigmoid(ew), zero counters ----------------
__global__ void prep_kernel(const float* __restrict__ ew, float* __restrict__ sigw,
                            int* __restrict__ cnt1, int* __restrict__ cnt2,
                            int N_e, int N_d) {
    int i = blockIdx.x * blockDim.x + threadIdx.x;
    if (i < N_e) { sigw[i] = 1.0f / (1.0f + expf(-ew[i])); cnt1[i] = 0; }
    if (i < N_d) cnt2[i] = 0;
}

// ---------------- prep: bf16 B-operand fragments for MFMA ----------------
// Bfrag[t][kk][lane][j] = Wcat[k = kk*32 + (lane>>4)*8 + j][n = t*16 + (lane&15)]
// where Wcat[k][n] = (k<128 ? Wself[n][k] : Wmsg[n][k-128])   (y = x @ W.T)
__global__ void wfrag_kernel(const float* __restrict__ Wself,
                             const float* __restrict__ Wmsg,
                             unsigned short* __restrict__ Bfrag) {
    int idx = blockIdx.x * blockDim.x + threadIdx.x;   // 0..32767
    int j    = idx & 7;
    int lane = (idx >> 3) & 63;
    int kk   = (idx >> 9) & 7;
    int t    = idx >> 12;
    int k = kk * 32 + ((lane >> 4) << 3) + j;
    int n = (t << 4) + (lane & 15);
    float w = (k < H) ? Wself[n * H + k] : Wmsg[n * H + (k - H)];
    Bfrag[idx] = f2bf(w);
}

// ---------------- CSR build ----------------
__global__ void hist_kernel(const int* __restrict__ e_d2e, const int* __restrict__ e_e2d,
                            int* __restrict__ cnt1, int* __restrict__ cnt2, int E) {
    int e = blockIdx.x * blockDim.x + threadIdx.x;
    if (e < E) {
        atomicAdd(&cnt1[e_d2e[E + e]], 1);
        atomicAdd(&cnt2[e_e2d[E + e]], 1);
    }
}

__global__ void scan_kernel(const int* __restrict__ cnt1, int* __restrict__ off1,
                            int* __restrict__ cur1, int N1,
                            const int* __restrict__ cnt2, int* __restrict__ off2,
                            int* __restrict__ cur2, int N2) {
    const int* cnt = blockIdx.x ? cnt2 : cnt1;
    int* off = blockIdx.x ? off2 : off1;
    int* cur = blockIdx.x ? cur2 : cur1;
    int N    = blockIdx.x ? N2 : N1;
    __shared__ int part[257];
    int tid = threadIdx.x;
    int chunk = (N + 255) / 256;
    int lo = tid * chunk, hi = min(lo + chunk, N);
    int s = 0;
    for (int i = lo; i < hi; ++i) s += cnt[i];
    part[tid] = s;
    __syncthreads();
    if (tid == 0) {
        int run = 0;
        for (int i = 0; i < 256; ++i) { int t = part[i]; part[i] = run; run += t; }
        part[256] = run;
    }
    __syncthreads();
    int run = part[tid];
    for (int i = lo; i < hi; ++i) { off[i] = run; cur[i] = run; run += cnt[i]; }
    if (tid == 0) off[N] = part[256];
}

__global__ void fill_kernel(const int* __restrict__ e_d2e, const int* __restrict__ e_e2d,
                            int* __restrict__ cur1, int* __restrict__ srcs1,
                            int* __restrict__ cur2, int* __restrict__ srcs2, int E) {
    int e = blockIdx.x * blockDim.x + threadIdx.x;
    if (e < E) {
        int p1 = atomicAdd(&cur1[e_d2e[E + e]], 1); srcs1[p1] = e_d2e[e];
        int p2 = atomicAdd(&cur2[e_e2d[E + e]], 1); srcs2[p2] = e_e2d[e];
    }
}

// ---------------- fused node update (MFMA + LDS-staged CSR) ----------------
// Block: 32 rows x 128 outputs. GEMM [32 x 256(K)] @ [256 x 128],
// A = [x_bf16 | S_bf16], B = [Wself^T; Wmsg^T] pre-fragmentized.
// Gather stage: 8 loads in flight per round (MLP=8) + one exec-masked
// 8-wide tail round -> typical row exposes ONE memory latency, not 2-5.
// XCD batch-affinity swizzle keeps each XCD's gathers in its L2/L3 slice.
__global__ __launch_bounds__(256, 8)
void node_update_kernel(const float* __restrict__ x,
                        const float* __restrict__ gsrc,
                        const int* __restrict__ off,
                        const int* __restrict__ srcs,
                        const float* __restrict__ sigw,     // null for phase D
                        const unsigned short* __restrict__ Bfrag,
                        const float* __restrict__ bias,
                        const float* __restrict__ gamma,
                        const float* __restrict__ beta,
                        float* __restrict__ out,
                        int nShift, int nMask, long gStride, int nrows) {
    __shared__ __align__(16) unsigned short Abuf[ROWS * ASTRIDE];
    __shared__ int idxbuf[IDXCAP];
    __shared__ int offs[ROWS + 1];
    float* XN = reinterpret_cast<float*>(Abuf);   // aliased: reused after MFMA

    const int tid  = threadIdx.x;
    // ---- XCD batch-affinity swizzle (bijective when gridDim.x % 8 == 0) ----
    int wg;
    {
        const int nwg = gridDim.x;
        const int bid = blockIdx.x;
        wg = ((nwg & 7) == 0) ? ((bid & 7) * (nwg >> 3) + (bid >> 3)) : bid;
    }
    const int row0 = wg * ROWS;
    const int n0   = row0 & nMask;     // rows are 32 consecutive n of one b (N % 32 == 0)

    // ---- stage CSR offsets + source indices into LDS ----
    if (tid <= ROWS) offs[tid] = off[n0 + tid];
    __syncthreads();
    const int jbase = offs[0];
    const int jtot  = offs[ROWS] - jbase;
    const int jlds  = min(jtot, IDXCAP);
    for (int j = tid; j < jlds; j += 256) idxbuf[j] = srcs[jbase + j];
    __syncthreads();

    // ---- stage: x -> bf16, scaled gather-sum -> bf16 (float4 per lane) ----
    {
        const int l32 = tid & 31;          // 32 lanes cover a 128-col row, 4 cols each
        const int sub = tid >> 5;          // 0..7: row within pass
        const int c0  = l32 * 4;
        const float* gb = gsrc + (size_t)(row0 >> nShift) * gStride;
        const bool allLds = (jtot <= IDXCAP);
        const floatx4 vzero = {0.f, 0.f, 0.f, 0.f};
#pragma unroll
        for (int pass = 0; pass < 4; ++pass) {
            const int r  = pass * 8 + sub;
            const int rg = row0 + r;
            floatx4 xv = vzero;
            floatx4 sv = vzero;
            if (rg < nrows) {
                xv = *reinterpret_cast<const floatx4*>(&x[(size_t)rg * H + c0]);
                const int beg = offs[r] - jbase, end = offs[r + 1] - jbase;
                int j = beg;
                if (allLds) {
                    // full 8-wide rounds: 8 independent 16B loads in flight
                    for (; j + 8 <= end; j += 8) {
                        int s0 = idxbuf[j + 0], s1 = idxbuf[j + 1];
                        int s2 = idxbuf[j + 2], s3 = idxbuf[j + 3];
                        int s4 = idxbuf[j + 4], s5 = idxbuf[j + 5];
                        int s6 = idxbuf[j + 6], s7 = idxbuf[j + 7];
                        floatx4 v0 = *reinterpret_cast<const floatx4*>(&gb[(size_t)s0 * H + c0]);
                        floatx4 v1 = *reinterpret_cast<const floatx4*>(&gb[(size_t)s1 * H + c0]);
                        floatx4 v2 = *reinterpret_cast<const floatx4*>(&gb[(size_t)s2 * H + c0]);
                        floatx4 v3 = *reinterpret_cast<const floatx4*>(&gb[(size_t)s3 * H + c0]);
                        floatx4 v4 = *reinterpret_cast<const floatx4*>(&gb[(size_t)s4 * H + c0]);
                        floatx4 v5 = *reinterpret_cast<const floatx4*>(&gb[(size_t)s5 * H + c0]);
                        floatx4 v6 = *reinterpret_cast<const floatx4*>(&gb[(size_t)s6 * H + c0]);
                        floatx4 v7 = *reinterpret_cast<const floatx4*>(&gb[(size_t)s7 * H + c0]);
                        sv += ((v0 + v1) + (v2 + v3)) + ((v4 + v5) + (v6 + v7));
                    }
                    // masked 8-wide tail (<=7 remaining): clamped idx keeps the
                    // address valid; predicated ?: zeroes past-end lanes. One
                    // latency exposure instead of a serial scalar tail.
                    if (j < end) {
                        const int e1 = end - 1;
                        int s0 = idxbuf[min(j + 0, e1)], s1 = idxbuf[min(j + 1, e1)];
                        int s2 = idxbuf[min(j + 2, e1)], s3 = idxbuf[min(j + 3, e1)];
                        int s4 = idxbuf[min(j + 4, e1)], s5 = idxbuf[min(j + 5, e1)];
                        int s6 = idxbuf[min(j + 6, e1)], s7 = idxbuf[min(j + 7, e1)];
                        floatx4 v0 = *reinterpret_cast<const floatx4*>(&gb[(size_t)s0 * H + c0]);
                        floatx4 v1 = (j + 1 < end) ? *reinterpret_cast<const floatx4*>(&gb[(size_t)s1 * H + c0]) : vzero;
                        floatx4 v2 = (j + 2 < end) ? *reinterpret_cast<const floatx4*>(&gb[(size_t)s2 * H + c0]) : vzero;
                        floatx4 v3 = (j + 3 < end) ? *reinterpret_cast<const floatx4*>(&gb[(size_t)s3 * H + c0]) : vzero;
                        floatx4 v4 = (j + 4 < end) ? *reinterpret_cast<const floatx4*>(&gb[(size_t)s4 * H + c0]) : vzero;
                        floatx4 v5 = (j + 5 < end) ? *reinterpret_cast<const floatx4*>(&gb[(size_t)s5 * H + c0]) : vzero;
                        floatx4 v6 = (j + 6 < end) ? *reinterpret_cast<const floatx4*>(&gb[(size_t)s6 * H + c0]) : vzero;
                        floatx4 v7 = (j + 7 < end) ? *reinterpret_cast<const floatx4*>(&gb[(size_t)s7 * H + c0]) : vzero;
                        sv += ((v0 + v1) + (v2 + v3)) + ((v4 + v5) + (v6 + v7));
                    }
                } else {
                    for (; j < end; ++j) {   // rare: block with >IDXCAP edges
                        int s = (j < IDXCAP) ? idxbuf[j] : srcs[jbase + j];
                        sv += *reinterpret_cast<const floatx4*>(&gb[(size_t)s * H + c0]);
                    }
                }
                float scale = (sigw ? sigw[n0 + r] : 1.0f) / fmaxf((float)(end - beg), 1.0f);
                sv *= scale;
            }
            ushortx4 xb, sb;
#pragma unroll
            for (int q = 0; q < 4; ++q) { xb[q] = f2bf(xv[q]); sb[q] = f2bf(sv[q]); }
            *reinterpret_cast<ushortx4*>(&Abuf[r * ASTRIDE + c0])     = xb;
            *reinterpret_cast<ushortx4*>(&Abuf[r * ASTRIDE + H + c0]) = sb;
        }
    }
    __syncthreads();

    const int wave = tid >> 6, lane = tid & 63;
    const int quad = lane >> 4, l16 = lane & 15;

    // ---- prefetch epilogue residual x into registers (lands under MFMA) ----
    float xpre[2][2][4];
#pragma unroll
    for (int mt = 0; mt < 2; ++mt)
#pragma unroll
        for (int t = 0; t < 2; ++t)
#pragma unroll
            for (int reg = 0; reg < 4; ++reg) {
                int r  = 16 * mt + quad * 4 + reg;
                int rg = row0 + r;
                int col = 32 * wave + 16 * t + l16;
                xpre[mt][t][reg] = (rg < nrows) ? x[(size_t)rg * H + col] : 0.f;
            }

    floatx4 acc[2][2];
#pragma unroll
    for (int mt = 0; mt < 2; ++mt)
#pragma unroll
        for (int t = 0; t < 2; ++t)
            acc[mt][t] = (floatx4){0.f, 0.f, 0.f, 0.f};

    // ---- MFMA main loop: K = 256 in 8 chunks of 32 ----
    const unsigned short* bf_base = Bfrag + (size_t)(2 * wave) * 4096;  // t stride = 8*64*8
    for (int kk = 0; kk < 8; ++kk) {
        const short8 b0 = *reinterpret_cast<const short8*>(bf_base + (kk * 64 + lane) * 8);
        const short8 b1 = *reinterpret_cast<const short8*>(bf_base + 4096 + (kk * 64 + lane) * 8);
#pragma unroll
        for (int mt = 0; mt < 2; ++mt) {
            const short8 a = *reinterpret_cast<const short8*>(
                &Abuf[(16 * mt + l16) * ASTRIDE + kk * 32 + quad * 8]);
            acc[mt][0] = __builtin_amdgcn_mfma_f32_16x16x32_bf16(a, b0, acc[mt][0], 0, 0, 0);
            acc[mt][1] = __builtin_amdgcn_mfma_f32_16x16x32_bf16(a, b1, acc[mt][1], 0, 0, 0);
        }
    }
    __syncthreads();   // all Abuf reads complete before XN overwrite

    // ---- epilogue 1: bias + ReLU + fp32 residual (prefetched x) -> XN ----
#pragma unroll
    for (int t = 0; t < 2; ++t) {
        int col = 32 * wave + 16 * t + l16;
        float bb = bias[col];
#pragma unroll
        for (int mt = 0; mt < 2; ++mt) {
#pragma unroll
            for (int reg = 0; reg < 4; ++reg) {
                int r  = 16 * mt + quad * 4 + reg;   // C/D: row = quad*4+reg, col = lane&15
                float pre = fmaxf(acc[mt][t][reg] + bb, 0.f);
                float xn  = xpre[mt][t][reg] + pre;
                XN[r * XSTRIDE + col] = xn;
            }
        }
    }
    __syncthreads();

    // ---- epilogue 2: LayerNorm (wave handles 8 rows; lane -> cols {lane, lane+64}) ----
    {
        const int o0 = lane, o1 = lane + 64;
        const float g0 = gamma[o0], g1 = gamma[o1];
        const float be0 = beta[o0], be1 = beta[o1];
        for (int rr = 0; rr < 8; ++rr) {
            int r  = 8 * wave + rr;
            int rg = row0 + r;
            if (rg >= nrows) break;
            float xn0 = XN[r * XSTRIDE + o0];
            float xn1 = XN[r * XSTRIDE + o1];
            float s  = xn0 + xn1;
            float s2 = xn0 * xn0 + xn1 * xn1;
#pragma unroll
            for (int m = 32; m >= 1; m >>= 1) {
                s  += __shfl_xor(s, m, 64);
                s2 += __shfl_xor(s2, m, 64);
            }
            float mean = s * (1.0f / H);
            float var  = s2 * (1.0f / H) - mean * mean;
            float rstd = rsqrtf(var + 1e-5f);
            out[(size_t)rg * H + o0] = (xn0 - mean) * rstd * g0 + be0;
            out[(size_t)rg * H + o1] = (xn1 - mean) * rstd * g1 + be1;
        }
    }
}

extern "C" void kernel_launch(void* const* d_in, const int* in_sizes, int n_in,
                              void* d_out, int out_size, void* d_ws, size_t ws_size,
                              hipStream_t stream) {
    const float* hD       = (const float*)d_in[0];
    const float* hE       = (const float*)d_in[1];
    const int*   e_d2e    = (const int*)d_in[2];
    const int*   e_e2d    = (const int*)d_in[3];
    const float* ew       = (const float*)d_in[4];
    const float* W_d2e    = (const float*)d_in[5];
    const float* W_e_self = (const float*)d_in[6];
    const float* b_e      = (const float*)d_in[7];
    const float* g_e      = (const float*)d_in[8];
    const float* beta_e   = (const float*)d_in[9];
    const float* W_e2d    = (const float*)d_in[10];
    const float* W_d_self = (const float*)d_in[11];
    const float* b_d      = (const float*)d_in[12];
    const float* g_d      = (const float*)d_in[13];
    const float* beta_d   = (const float*)d_in[14];

    const int E   = in_sizes[2] / 2;
    const int N_e = in_sizes[4];
    const int Bsz = in_sizes[1] / (N_e * H);
    const int N_d = in_sizes[0] / (Bsz * H);

    float* outD = (float*)d_out;
    float* outE = (float*)d_out + (size_t)Bsz * N_d * H;

    char* p = (char*)d_ws;
    auto alloc = [&](size_t bytes) { char* r = p; p += (bytes + 255) & ~(size_t)255; return r; };
    int*   cnt1   = (int*)alloc((size_t)N_e * 4);
    int*   off1   = (int*)alloc((size_t)(N_e + 1) * 4);
    int*   cur1   = (int*)alloc((size_t)N_e * 4);
    int*   srcs1  = (int*)alloc((size_t)E * 4);
    int*   cnt2   = (int*)alloc((size_t)N_d * 4);
    int*   off2   = (int*)alloc((size_t)(N_d + 1) * 4);
    int*   cur2   = (int*)alloc((size_t)N_d * 4);
    int*   srcs2  = (int*)alloc((size_t)E * 4);
    float* sigw   = (float*)alloc((size_t)N_e * 4);
    unsigned short* BfragB = (unsigned short*)alloc((size_t)32768 * 2);  // phase B weights
    unsigned short* BfragD = (unsigned short*)alloc((size_t)32768 * 2);  // phase D weights

    int prepN = (N_e > N_d) ? N_e : N_d;
    prep_kernel<<<(prepN + 255) / 256, 256, 0, stream>>>(ew, sigw, cnt1, cnt2, N_e, N_d);
    wfrag_kernel<<<128, 256, 0, stream>>>(W_e_self, W_d2e, BfragB);
    wfrag_kernel<<<128, 256, 0, stream>>>(W_d_self, W_e2d, BfragD);
    hist_kernel<<<(E + 255) / 256, 256, 0, stream>>>(e_d2e, e_e2d, cnt1, cnt2, E);
    scan_kernel<<<2, 256, 0, stream>>>(cnt1, off1, cur1, N_e, cnt2, off2, cur2, N_d);
    fill_kernel<<<(E + 255) / 256, 256, 0, stream>>>(e_d2e, e_e2d, cur1, srcs1, cur2, srcs2, E);

    // Phase B: E-node update (gathers hD via CSR1, sigmoid weights)
    int rowsB = Bsz * N_e;
    int shB = __builtin_ctz(N_e);
    node_update_kernel<<<(rowsB + ROWS - 1) / ROWS, 256, 0, stream>>>(
        hE, hD, off1, srcs1, sigw, BfragB, b_e, g_e, beta_e, outE,
        shB, N_e - 1, (long)N_d * H, rowsB);

    // Phase D: D-node update (gathers hE_new from d_out via CSR2)
    int rowsD = Bsz * N_d;
    int shD = __builtin_ctz(N_d);
    node_update_kernel<<<(rowsD + ROWS - 1) / ROWS, 256, 0, stream>>>(
        hD, outE, off2, srcs2, nullptr, BfragD, b_d, g_d, beta_d, outD,
        shD, N_d - 1, (long)N_e * H, rowsD);
}